// Round 7
// baseline (913.075 us; speedup 1.0000x reference)
//
#include <hip/hip_runtime.h>
#include <hip/hip_bf16.h>

// Self-attention: context = softmax((X@Wq)(X@Wk)^T / sqrt(d)) @ X
// N=8192, d=1024, fp32. Near-one-hot scores => fp32-grade score accuracy:
// f16 split (hi+lo, 3-term Ootomo) MFMA GEMMs for projections and QK^T;
// plain f16 MFMA for P@V.
//
// R7: (a) inner loop -> mfma_f32_32x32x16_f16 (32k FLOP/inst @ ~8.07cyc vs
//     2x16k @ 9.7; half the MFMA instructions, same LDS bytes/FLOP).
//     C/D: col=lane&31, row=(reg&3)+8*(reg>>2)+4*(lane>>5) [m74/m101].
//     A/B frag: m=lane&31, k=(lane>>5)*8+j (analog of verified 16x16 map).
//     (b) PV SWAP=0 (grid 8x64x2): id%8=col-block -> per-XCD XT slice
//     2 MB, L2-resident (SWAP=1 thrashed 16 MB/XCD; FETCH 206 vs 144 ideal).

typedef _Float16 f16x8 __attribute__((ext_vector_type(8)));
typedef _Float16 f16x4 __attribute__((ext_vector_type(4)));
typedef float    f32x16 __attribute__((ext_vector_type(16)));

#define TM 128
#define TN 128

// async global->LDS, 16 B per lane; LDS dest = wave-uniform base + lane*16
__device__ __forceinline__ void g2lds16(const _Float16* g, _Float16* l) {
    __builtin_amdgcn_global_load_lds(
        (__attribute__((address_space(1))) unsigned int*)(g),
        (__attribute__((address_space(3))) unsigned int*)(l),
        16, 0, 0);
}

// ---------------------------------------------------------------- helpers

// split fp32 -> f16 hi + f16 lo (x ~= hi + lo, residual ~ |x|*2^-22)
__global__ __launch_bounds__(256) void split_rows(const float* __restrict__ src,
                                                  _Float16* __restrict__ hi,
                                                  _Float16* __restrict__ lo,
                                                  long n) {
    long i = (long)blockIdx.x * blockDim.x + threadIdx.x;
    long stride = (long)gridDim.x * blockDim.x;
    for (; i < n; i += stride) {
        float v = src[i];
        _Float16 h = (_Float16)v;
        hi[i] = h;
        lo[i] = (_Float16)(v - (float)h);
    }
}

// dst[c][r] = src[r][c]; optional lo-part output (nullptr => hi only)
__global__ void transpose_split(const float* __restrict__ src,
                                _Float16* __restrict__ dhi,
                                _Float16* __restrict__ dlo,
                                int R, int C) {
    __shared__ float tile[32][33];
    int c0 = blockIdx.x * 32, r0 = blockIdx.y * 32;
    int tx = threadIdx.x, ty = threadIdx.y;   // (32, 8)
#pragma unroll
    for (int k = 0; k < 4; ++k)
        tile[ty + 8 * k][tx] = src[(size_t)(r0 + ty + 8 * k) * C + c0 + tx];
    __syncthreads();
#pragma unroll
    for (int k = 0; k < 4; ++k) {
        float v = tile[tx][ty + 8 * k];
        _Float16 h = (_Float16)v;
        size_t idx = (size_t)(c0 + ty + 8 * k) * R + r0 + tx;
        dhi[idx] = h;
        if (dlo) dlo[idx] = (_Float16)(v - (float)h);
    }
}

// out = a + b (final split-K reduction), float4 grid-stride
__global__ __launch_bounds__(256) void add_rows(const float* __restrict__ a,
                                                const float* __restrict__ b,
                                                float* __restrict__ out, long n4) {
    long i = (long)blockIdx.x * blockDim.x + threadIdx.x;
    long stride = (long)gridDim.x * blockDim.x;
    for (; i < n4; i += stride) {
        float4 x = ((const float4*)a)[i];
        float4 y = ((const float4*)b)[i];
        x.x += y.x; x.y += y.y; x.z += y.z; x.w += y.w;
        ((float4*)out)[i] = x;
    }
}

// ---------------------------------------------------------------- GEMM
// C[M,N] fp32 = sum_k A[M,K] * B_bt[N,K]^T  (row-major; B in transposed form).
// TERMS==3: A = Ahi+Alo, B = Bhi+Blo, compute hh + hl + lh (Ootomo 3-term).
// SPLIT_OUT==1: epilogue stores f16 hi/lo pair instead of fp32.
// SWAP==1: blockIdx.x indexes row-blocks (A-reuse XCD-co-located).
// BKH: k-step in halves (32 or 64); LDS row = BKH halves, XOR-swizzled.
// gridDim.z slices via element offsets zA/zB/zC (fused proj / split-K PV).
template <int TERMS, int SPLIT_OUT, int SWAP, int BKH>
__global__ __launch_bounds__(256, TERMS == 3 ? 3 : 4) void gemm_bt(
    const _Float16* __restrict__ Ahi, const _Float16* __restrict__ Alo,
    const _Float16* __restrict__ Bhi, const _Float16* __restrict__ Blo,
    float* __restrict__ C, _Float16* __restrict__ Chi, _Float16* __restrict__ Clo,
    long lda, long ldb, long ldc, int K, long zA, long zB, long zC) {
    constexpr int NBUF = (TERMS == 3) ? 4 : 2;     // hi/lo x A/B  or  A/B
    __shared__ __align__(16) _Float16 s[NBUF * 128 * BKH];

    const long z = blockIdx.z;
    Ahi += z * zA;
    Bhi += z * zB;
    if constexpr (TERMS == 3) { Alo += z * zA; Blo += z * zB; }
    if constexpr (SPLIT_OUT) { Chi += z * zC; Clo += z * zC; }
    else C += z * zC;

    const int t = threadIdx.x;
    const int wave = t >> 6;
    const int lane = t & 63;
    const int m32 = lane & 31;    // row/col within 32-tile
    const int kh = lane >> 5;     // k-half selector (8-half group)
    const int wr = wave >> 1;     // wave row 0..1
    const int wc = wave & 1;      // wave col 0..1

    const long rowBase = (long)(SWAP ? blockIdx.x : blockIdx.y) * TM;
    const long colBase = (long)(SWAP ? blockIdx.y : blockIdx.x) * TN;

    // --- staging assignment (per wave) ---
    const _Float16* src;
    long myLd, gRow0;
    int ldsBaseH;
    if constexpr (TERMS == 3) {
        // wave 0: Ahi  1: Alo  2: Bhi  3: Blo ; 128 rows each
        const _Float16* a = (wave & 1) ? Alo : Ahi;
        const _Float16* b = (wave & 1) ? Blo : Bhi;
        src = (wave & 2) ? b : a;
        myLd = (wave & 2) ? ldb : lda;
        gRow0 = (wave & 2) ? colBase : rowBase;
        ldsBaseH = wave * (128 * BKH);
    } else {
        // wave 0: A rows 0-63  1: A rows 64-127  2: B 0-63  3: B 64-127
        src = (wave & 2) ? Bhi : Ahi;
        myLd = (wave & 2) ? ldb : lda;
        gRow0 = ((wave & 2) ? colBase : rowBase) + (wave & 1) * 64;
        ldsBaseH = (wave >> 1) * (128 * BKH) + (wave & 1) * (64 * BKH);
    }
    // lanes per row / rows per 1KB issue; 8 issues cover the wave's rows.
    constexpr int LPR = BKH / 8;          // 4 (BKH=32) or 8 (BKH=64)
    constexpr int RPI = 64 / LPR;         // 16 or 8
    constexpr int NISS = (TERMS == 3 ? 128 : 64) / RPI;   // 8 both ways
    const int lr = lane / LPR;            // row within issue
    const int slot = lane % LPR;          // 16B column slot
    // XOR swizzle: LDS[row][slot] holds global col group slot^swz(row).
    // issues stride RPI rows, so row mod RPI is lane-invariant across j.
    const int swzW = (BKH == 32) ? ((lr >> 1) & 3) : (lr & 7);
    const _Float16* rp = src + (gRow0 + lr) * myLd + (slot ^ swzW) * 8;
    _Float16* ldsW = &s[ldsBaseH];

    const _Float16* sAh = s;
    const _Float16* sBh = s + (TERMS == 3 ? 2 : 1) * 128 * BKH;
    const _Float16* sAl = s + 128 * BKH;       // TERMS==3 only
    const _Float16* sBl = s + 3 * 128 * BKH;   // TERMS==3 only

    // reader-side swizzle: row = (wave/tile)*32|64 + m32; offsets of 32/64
    // leave both swz fns invariant, so compute from m32 once.
    const int swzR = (BKH == 32) ? ((m32 >> 1) & 3) : (m32 & 7);

    f32x16 acc[2][2];
#pragma unroll
    for (int r = 0; r < 2; ++r)
#pragma unroll
        for (int c = 0; c < 2; ++c)
#pragma unroll
            for (int i = 0; i < 16; ++i) acc[r][c][i] = 0.0f;

    for (int k0 = 0; k0 < K; k0 += BKH) {
        __syncthreads();   // LDS safe to overwrite
#pragma unroll
        for (int j = 0; j < NISS; ++j)
            g2lds16(rp + (long)(j * RPI) * myLd + k0, ldsW + j * 512);
        __syncthreads();   // drains vmcnt before barrier => data visible

#pragma unroll
        for (int ks = 0; ks < BKH / 16; ++ks) {
            const int grp = ks * 2 + kh;   // 8-half group within LDS row
            f16x8 ah[2], bh[2], al[2], bl[2];
#pragma unroll
            for (int r = 0; r < 2; ++r) {
                int ra = (wr * 64 + r * 32 + m32) * BKH + (grp ^ swzR) * 8;
                int rb = (wc * 64 + r * 32 + m32) * BKH + (grp ^ swzR) * 8;
                ah[r] = *(const f16x8*)&sAh[ra];
                bh[r] = *(const f16x8*)&sBh[rb];
                if constexpr (TERMS == 3) {
                    al[r] = *(const f16x8*)&sAl[ra];
                    bl[r] = *(const f16x8*)&sBl[rb];
                }
            }
#pragma unroll
            for (int r = 0; r < 2; ++r)
#pragma unroll
                for (int c = 0; c < 2; ++c) {
                    acc[r][c] = __builtin_amdgcn_mfma_f32_32x32x16_f16(
                        ah[r], bh[c], acc[r][c], 0, 0, 0);
                    if constexpr (TERMS == 3) {
                        acc[r][c] = __builtin_amdgcn_mfma_f32_32x32x16_f16(
                            ah[r], bl[c], acc[r][c], 0, 0, 0);
                        acc[r][c] = __builtin_amdgcn_mfma_f32_32x32x16_f16(
                            al[r], bh[c], acc[r][c], 0, 0, 0);
                    }
                }
        }
    }

    // 32x32 C/D layout: col=lane&31, row=(reg&3)+8*(reg>>2)+4*(lane>>5)
    // (verified m74/m101, dtype-independent)
#pragma unroll
    for (int r = 0; r < 2; ++r)
#pragma unroll
        for (int c = 0; c < 2; ++c)
#pragma unroll
            for (int i = 0; i < 16; ++i) {
                long row = rowBase + wr * 64 + r * 32 +
                           (i & 3) + 8 * (i >> 2) + 4 * kh;
                long col = colBase + wc * 64 + c * 32 + m32;
                if constexpr (SPLIT_OUT) {
                    float v = acc[r][c][i];
                    _Float16 h = (_Float16)v;
                    Chi[row * ldc + col] = h;
                    Clo[row * ldc + col] = (_Float16)(v - (float)h);
                } else {
                    C[row * ldc + col] = acc[r][c][i];
                }
            }
}

// ---------------------------------------------------------------- softmax
// One block per row (8192 fp32). Whole row into registers (float4), reduce
// max and sum(exp), write P f16 (may alias the fp32 row in-place: all reads
// complete before first barrier, writes after last). Scale 1/32 folded in.
__global__ __launch_bounds__(256) void softmax_rows(const float* __restrict__ S,
                                                    _Float16* __restrict__ P,
                                                    long ldp, int N) {
    const int row = blockIdx.x;
    const int t = threadIdx.x;
    const float4* rowp = (const float4*)(S + (size_t)row * N);
    float4 v[8];
    float mx = -3.4e38f;
#pragma unroll
    for (int i = 0; i < 8; ++i) {
        v[i] = rowp[t + 256 * i];
        mx = fmaxf(mx, fmaxf(fmaxf(v[i].x, v[i].y), fmaxf(v[i].z, v[i].w)));
    }
    __shared__ float red[8];
#pragma unroll
    for (int off = 32; off >= 1; off >>= 1) mx = fmaxf(mx, __shfl_xor(mx, off));
    if ((t & 63) == 0) red[t >> 6] = mx;
    __syncthreads();
    mx = fmaxf(fmaxf(red[0], red[1]), fmaxf(red[2], red[3]));

    float sum = 0.0f;
#pragma unroll
    for (int i = 0; i < 8; ++i) {
        v[i].x = __expf((v[i].x - mx) * 0.03125f);
        v[i].y = __expf((v[i].y - mx) * 0.03125f);
        v[i].z = __expf((v[i].z - mx) * 0.03125f);
        v[i].w = __expf((v[i].w - mx) * 0.03125f);
        sum += (v[i].x + v[i].y) + (v[i].z + v[i].w);
    }
#pragma unroll
    for (int off = 32; off >= 1; off >>= 1) sum += __shfl_xor(sum, off);
    if ((t & 63) == 0) red[4 + (t >> 6)] = sum;
    __syncthreads();
    float inv = 1.0f / (red[4] + red[5] + red[6] + red[7]);

    f16x4* prow = (f16x4*)(P + (size_t)row * ldp);
#pragma unroll
    for (int i = 0; i < 8; ++i) {
        f16x4 o;
        o[0] = (_Float16)(v[i].x * inv);
        o[1] = (_Float16)(v[i].y * inv);
        o[2] = (_Float16)(v[i].z * inv);
        o[3] = (_Float16)(v[i].w * inv);
        prow[t + 256 * i] = o;
    }
}

// ---------------------------------------------------------------- launch
extern "C" void kernel_launch(void* const* d_in, const int* in_sizes, int n_in,
                              void* d_out, int out_size, void* d_ws, size_t ws_size,
                              hipStream_t stream) {
    const float* X  = (const float*)d_in[0];  // [8192,1024]
    const float* Wq = (const float*)d_in[1];  // [1024,1024]
    const float* Wk = (const float*)d_in[2];  // [1024,1024]
    float* out = (float*)d_out;               // [8192,1024]

    const long Nt = 8192, D = 1024;
    char* ws = (char*)d_ws;
    const size_t MB = 1024ull * 1024ull;

    // Persistent region (80 MB):
    _Float16* XT  = (_Float16*)(ws + 0);        // 16 MB [1024][8192] = X^T f16
    _Float16* Qhi = (_Float16*)(ws + 16 * MB);  // 16 MB   (dead after S-GEMMs;
    _Float16* Qlo = (_Float16*)(ws + 32 * MB);  //          reused as PK0/PK1)
    _Float16* Khi = (_Float16*)(ws + 48 * MB);
    _Float16* Klo = (_Float16*)(ws + 64 * MB);
    // Transient (dead after projections):
    _Float16* Xhi   = (_Float16*)(ws + 80 * MB);   // 16 MB
    _Float16* Xlo   = (_Float16*)(ws + 96 * MB);   // 16 MB
    _Float16* WqThi = (_Float16*)(ws + 112 * MB);  // 2 MB each, Wq/Wk adjacent
    _Float16* WqTlo = (_Float16*)(ws + 114 * MB);
    _Float16* WkThi = (_Float16*)(ws + 116 * MB);
    _Float16* WkTlo = (_Float16*)(ws + 118 * MB);
    // PV split-K partials (alias dead Qhi..Klo): 2 x 32 MB fp32
    float* PK0 = (float*)(ws + 16 * MB);

    const size_t rowBytes = (size_t)Nt * 4;  // 32 KB per S row
    const bool planA = ws_size >= 208 * MB + 128 * rowBytes;
    _Float16* Pbuf = (_Float16*)(ws + 80 * MB);   // plan A: 128 MB compact P
    float* Sc;
    long chunk;
    if (planA) {
        Sc = (float*)(ws + 208 * MB);
        size_t avail = ws_size - 208 * MB;
        chunk = (long)((avail / rowBytes / 128) * 128);
    } else {
        Sc = (float*)(ws + 80 * MB);
        size_t avail = ws_size > 80 * MB ? ws_size - 80 * MB : 0;
        chunk = (long)((avail / rowBytes / 128) * 128);
        if (chunk < 128) chunk = 128;  // last resort; smaller ws cannot work
    }
    if (chunk > Nt) chunk = Nt;
    // even-size chunks (avoid a tiny low-occupancy tail chunk)
    {
        long nch = (Nt + chunk - 1) / chunk;
        chunk = (((Nt + nch - 1) / nch) + 127) / 128 * 128;
    }

    // 1. prep: transpose X (f16 V^T), split X, transpose+split weights
    transpose_split<<<dim3(32, 256), dim3(32, 8), 0, stream>>>(X, XT, nullptr,
                                                               (int)Nt, (int)D);
    split_rows<<<1024, 256, 0, stream>>>(X, Xhi, Xlo, Nt * D);
    transpose_split<<<dim3(32, 32), dim3(32, 8), 0, stream>>>(Wq, WqThi, WqTlo,
                                                              (int)D, (int)D);
    transpose_split<<<dim3(32, 32), dim3(32, 8), 0, stream>>>(Wk, WkThi, WkTlo,
                                                              (int)D, (int)D);

    // 2. fused Q+K projections (3-term split), z=0 -> Q, z=1 -> K.
    //    zB = WkThi-WqThi = 4 MB = 2M halves; zC = Khi-Qhi = 16M halves.
    gemm_bt<3, 1, 1, 32><<<dim3(Nt / TM, D / TN, 2), 256, 0, stream>>>(
        Xhi, Xlo, WqThi, WqTlo, nullptr, Qhi, Qlo, D, D, D, (int)D,
        0, (long)(4 * MB / 2), (long)(32 * MB / 2));

    // 3. chunks: S = Q@K^T (3-term, fp32), softmax -> P f16.
    //    SWAP=0: grid.x = 64 col-blocks (B = K-splits, 32 MB, co-located).
    long done = 0;
    while (done < Nt) {
        long cur = Nt - done < chunk ? Nt - done : chunk;
        gemm_bt<3, 0, 0, 32><<<dim3(Nt / TN, cur / TM, 1), 256, 0, stream>>>(
            Qhi + done * D, Qlo + done * D, Khi, Klo, Sc, nullptr, nullptr,
            D, D, Nt, (int)D, 0, 0, 0);
        if (planA) {
            softmax_rows<<<(int)cur, 256, 0, stream>>>(Sc, Pbuf + done * Nt,
                                                       Nt, (int)Nt);
        } else {
            softmax_rows<<<(int)cur, 256, 0, stream>>>(Sc, (_Float16*)Sc,
                                                       2 * Nt, (int)Nt);
            gemm_bt<1, 0, 0, 64><<<dim3(D / TN, cur / TM, 1), 256, 0, stream>>>(
                (const _Float16*)Sc, nullptr, XT, nullptr,
                out + done * D, nullptr, nullptr, 2 * Nt, Nt, D, (int)Nt,
                0, 0, 0);
        }
        done += cur;
    }

    // 4. plan A: PV split-K=2, BK=64, SWAP=0: grid (8,64,2) -> id%8 =
    //    col-block -> per-XCD XT working set 2x1 MB (L2-resident); P tiles
    //    are unique per block (fetched once). Partials in dead Q/K region.
    if (planA) {
        gemm_bt<1, 0, 0, 64><<<dim3(D / TN, Nt / TM, 2), 256, 0, stream>>>(
            Pbuf, nullptr, XT, nullptr, PK0, nullptr, nullptr,
            Nt, Nt, D, (int)(Nt / 2),
            Nt / 2, Nt / 2, Nt * D);
        add_rows<<<1024, 256, 0, stream>>>(PK0, PK0 + Nt * D, out, Nt * D / 4);
    }
}

// Round 8
// 814.411 us; speedup vs baseline: 1.1211x; 1.1211x over previous
//
#include <hip/hip_runtime.h>
#include <hip/hip_bf16.h>

// Self-attention: context = softmax((X@Wq)(X@Wk)^T / sqrt(d)) @ X
// N=8192, d=1024, fp32. Near-one-hot scores => fp32-grade score accuracy:
// f16 split (hi+lo, 3-term Ootomo) MFMA GEMMs for projections and QK^T;
// plain f16 MFMA for P@V.
//
// R8: revert R7 (32x32 MFMA re-introduced 4-way LDS conflicts 1.678e7;
//     PV SWAP=0 thrashed L2, FETCH 540 MB). Back to R6's verified
//     16x16 + swizzle (0 conflicts) + PV SWAP=1. New: TERMS=3 occupancy
//     3->4 blocks/CU (proj's 1024 blocks fully resident; S-GEMM 16
//     waves/CU), fused X prep (1 pass: Xhi+Xlo+XT), paired-16B softmax IO.

typedef _Float16 f16x8 __attribute__((ext_vector_type(8)));
typedef _Float16 f16x4 __attribute__((ext_vector_type(4)));
typedef float    f32x4 __attribute__((ext_vector_type(4)));

#define TM 128
#define TN 128

// async global->LDS, 16 B per lane; LDS dest = wave-uniform base + lane*16
__device__ __forceinline__ void g2lds16(const _Float16* g, _Float16* l) {
    __builtin_amdgcn_global_load_lds(
        (__attribute__((address_space(1))) unsigned int*)(g),
        (__attribute__((address_space(3))) unsigned int*)(l),
        16, 0, 0);
}

// ---------------------------------------------------------------- helpers

// one pass over X: write Xhi/Xlo (row-major split) and XT (f16 transpose)
__global__ void prep_x(const float* __restrict__ src,
                       _Float16* __restrict__ hi, _Float16* __restrict__ lo,
                       _Float16* __restrict__ xt, int R, int C) {
    __shared__ float tile[32][33];
    int c0 = blockIdx.x * 32, r0 = blockIdx.y * 32;
    int tx = threadIdx.x, ty = threadIdx.y;   // (32, 8)
#pragma unroll
    for (int k = 0; k < 4; ++k) {
        int r = ty + 8 * k;
        size_t idx = (size_t)(r0 + r) * C + c0 + tx;
        float v = src[idx];
        tile[r][tx] = v;
        _Float16 h = (_Float16)v;
        hi[idx] = h;
        lo[idx] = (_Float16)(v - (float)h);
    }
    __syncthreads();
#pragma unroll
    for (int k = 0; k < 4; ++k) {
        float v = tile[tx][ty + 8 * k];
        xt[(size_t)(c0 + ty + 8 * k) * R + r0 + tx] = (_Float16)v;
    }
}

// dst[c][r] = src[r][c] with f16 hi/lo split (weights)
__global__ void transpose_split(const float* __restrict__ src,
                                _Float16* __restrict__ dhi,
                                _Float16* __restrict__ dlo,
                                int R, int C) {
    __shared__ float tile[32][33];
    int c0 = blockIdx.x * 32, r0 = blockIdx.y * 32;
    int tx = threadIdx.x, ty = threadIdx.y;   // (32, 8)
#pragma unroll
    for (int k = 0; k < 4; ++k)
        tile[ty + 8 * k][tx] = src[(size_t)(r0 + ty + 8 * k) * C + c0 + tx];
    __syncthreads();
#pragma unroll
    for (int k = 0; k < 4; ++k) {
        float v = tile[tx][ty + 8 * k];
        _Float16 h = (_Float16)v;
        size_t idx = (size_t)(c0 + ty + 8 * k) * R + r0 + tx;
        dhi[idx] = h;
        dlo[idx] = (_Float16)(v - (float)h);
    }
}

// out = a + b (final split-K reduction), float4 grid-stride
__global__ __launch_bounds__(256) void add_rows(const float* __restrict__ a,
                                                const float* __restrict__ b,
                                                float* __restrict__ out, long n4) {
    long i = (long)blockIdx.x * blockDim.x + threadIdx.x;
    long stride = (long)gridDim.x * blockDim.x;
    for (; i < n4; i += stride) {
        float4 x = ((const float4*)a)[i];
        float4 y = ((const float4*)b)[i];
        x.x += y.x; x.y += y.y; x.z += y.z; x.w += y.w;
        ((float4*)out)[i] = x;
    }
}

// ---------------------------------------------------------------- GEMM
// C[M,N] fp32 = sum_k A[M,K] * B_bt[N,K]^T  (row-major; B in transposed form).
// TERMS==3: A = Ahi+Alo, B = Bhi+Blo, compute hh + hl + lh (Ootomo 3-term).
// SPLIT_OUT==1: epilogue stores f16 hi/lo pair instead of fp32.
// SWAP==1: blockIdx.x indexes row-blocks (A-reuse XCD-co-located).
// BKH: k-step in halves (32 or 64); LDS row = BKH halves, XOR-swizzled.
// gridDim.z slices via element offsets zA/zB/zC (fused proj / split-K PV).
template <int TERMS, int SPLIT_OUT, int SWAP, int BKH>
__global__ __launch_bounds__(256, 4) void gemm_bt(
    const _Float16* __restrict__ Ahi, const _Float16* __restrict__ Alo,
    const _Float16* __restrict__ Bhi, const _Float16* __restrict__ Blo,
    float* __restrict__ C, _Float16* __restrict__ Chi, _Float16* __restrict__ Clo,
    long lda, long ldb, long ldc, int K, long zA, long zB, long zC) {
    constexpr int NBUF = (TERMS == 3) ? 4 : 2;     // hi/lo x A/B  or  A/B
    __shared__ __align__(16) _Float16 s[NBUF * 128 * BKH];

    const long z = blockIdx.z;
    Ahi += z * zA;
    Bhi += z * zB;
    if constexpr (TERMS == 3) { Alo += z * zA; Blo += z * zB; }
    if constexpr (SPLIT_OUT) { Chi += z * zC; Clo += z * zC; }
    else C += z * zC;

    const int t = threadIdx.x;
    const int wave = t >> 6;
    const int lane = t & 63;
    const int lm = lane & 15;     // row/col within 16-tile
    const int lq = lane >> 4;     // quad 0..3
    const int wr = wave >> 1;     // wave row 0..1
    const int wc = wave & 1;      // wave col 0..1

    const long rowBase = (long)(SWAP ? blockIdx.x : blockIdx.y) * TM;
    const long colBase = (long)(SWAP ? blockIdx.y : blockIdx.x) * TN;

    // --- staging assignment (per wave) ---
    const _Float16* src;
    long myLd, gRow0;
    int ldsBaseH;
    if constexpr (TERMS == 3) {
        // wave 0: Ahi  1: Alo  2: Bhi  3: Blo ; 128 rows each
        const _Float16* a = (wave & 1) ? Alo : Ahi;
        const _Float16* b = (wave & 1) ? Blo : Bhi;
        src = (wave & 2) ? b : a;
        myLd = (wave & 2) ? ldb : lda;
        gRow0 = (wave & 2) ? colBase : rowBase;
        ldsBaseH = wave * (128 * BKH);
    } else {
        // wave 0: A rows 0-63  1: A rows 64-127  2: B 0-63  3: B 64-127
        src = (wave & 2) ? Bhi : Ahi;
        myLd = (wave & 2) ? ldb : lda;
        gRow0 = ((wave & 2) ? colBase : rowBase) + (wave & 1) * 64;
        ldsBaseH = (wave >> 1) * (128 * BKH) + (wave & 1) * (64 * BKH);
    }
    // lanes per row / rows per 1KB issue; 8 issues cover the wave's rows.
    constexpr int LPR = BKH / 8;          // 4 (BKH=32) or 8 (BKH=64)
    constexpr int RPI = 64 / LPR;         // 16 or 8
    constexpr int NISS = (TERMS == 3 ? 128 : 64) / RPI;   // 8 both ways
    const int lr = lane / LPR;            // row within issue
    const int slot = lane % LPR;          // 16B column slot
    // XOR swizzle: LDS[row][slot] holds global col group slot^swz(row).
    // issues stride RPI rows, so row mod RPI is lane-invariant across j.
    const int swzW = (BKH == 32) ? ((lr >> 1) & 3) : (lr & 7);
    const _Float16* rp = src + (gRow0 + lr) * myLd + (slot ^ swzW) * 8;
    _Float16* ldsW = &s[ldsBaseH];

    const _Float16* sAh = s;
    const _Float16* sBh = s + (TERMS == 3 ? 2 : 1) * 128 * BKH;
    const _Float16* sAl = s + 128 * BKH;       // TERMS==3 only
    const _Float16* sBl = s + 3 * 128 * BKH;   // TERMS==3 only

    // reader-side swizzle (row = 64/16-aligned base + lm; offsets of 16/64
    // leave both swz fns invariant w.r.t. the bits used)
    const int swzR = (BKH == 32) ? ((lm >> 1) & 3) : (lm & 7);

    f32x4 acc[4][4];
#pragma unroll
    for (int r = 0; r < 4; ++r)
#pragma unroll
        for (int c = 0; c < 4; ++c)
#pragma unroll
            for (int i = 0; i < 4; ++i) acc[r][c][i] = 0.0f;

    for (int k0 = 0; k0 < K; k0 += BKH) {
        __syncthreads();   // LDS safe to overwrite
#pragma unroll
        for (int j = 0; j < NISS; ++j)
            g2lds16(rp + (long)(j * RPI) * myLd + k0, ldsW + j * 512);
        __syncthreads();   // drains vmcnt before barrier => data visible

#pragma unroll
        for (int kk = 0; kk < BKH; kk += 32) {
            const int gb = kk >> 3;   // column-group base (8 halves/group)
            f16x8 ah[4], bh[4], al[4], bl[4];
#pragma unroll
            for (int r = 0; r < 4; ++r) {
                int ra = (wr * 64 + r * 16 + lm) * BKH + ((gb + lq) ^ swzR) * 8;
                int rb = (wc * 64 + r * 16 + lm) * BKH + ((gb + lq) ^ swzR) * 8;
                ah[r] = *(const f16x8*)&sAh[ra];
                bh[r] = *(const f16x8*)&sBh[rb];
                if constexpr (TERMS == 3) {
                    al[r] = *(const f16x8*)&sAl[ra];
                    bl[r] = *(const f16x8*)&sBl[rb];
                }
            }
#pragma unroll
            for (int r = 0; r < 4; ++r)
#pragma unroll
                for (int c = 0; c < 4; ++c) {
                    acc[r][c] = __builtin_amdgcn_mfma_f32_16x16x32_f16(
                        ah[r], bh[c], acc[r][c], 0, 0, 0);
                    if constexpr (TERMS == 3) {
                        acc[r][c] = __builtin_amdgcn_mfma_f32_16x16x32_f16(
                            ah[r], bl[c], acc[r][c], 0, 0, 0);
                        acc[r][c] = __builtin_amdgcn_mfma_f32_16x16x32_f16(
                            al[r], bh[c], acc[r][c], 0, 0, 0);
                    }
                }
        }
    }

    // C/D layout: col = lane&15, row = quad*4 + reg  (verified m89/m91)
#pragma unroll
    for (int r = 0; r < 4; ++r)
#pragma unroll
        for (int c = 0; c < 4; ++c)
#pragma unroll
            for (int i = 0; i < 4; ++i) {
                long row = rowBase + wr * 64 + r * 16 + lq * 4 + i;
                long col = colBase + wc * 64 + c * 16 + lm;
                if constexpr (SPLIT_OUT) {
                    float v = acc[r][c][i];
                    _Float16 h = (_Float16)v;
                    Chi[row * ldc + col] = h;
                    Clo[row * ldc + col] = (_Float16)(v - (float)h);
                } else {
                    C[row * ldc + col] = acc[r][c][i];
                }
            }
}

// ---------------------------------------------------------------- softmax
// One block per row (8192 fp32). Whole row into registers (paired float4 =
// 32 B/lane contiguous), reduce max and sum(exp), write P f16 as 16 B
// chunks (may alias the fp32 row in-place: all reads complete before the
// first barrier, writes after the last). Scale 1/32 folded in.
__global__ __launch_bounds__(256) void softmax_rows(const float* __restrict__ S,
                                                    _Float16* __restrict__ P,
                                                    long ldp, int N) {
    const int row = blockIdx.x;
    const int t = threadIdx.x;
    const float4* rowp = (const float4*)(S + (size_t)row * N);
    float4 v[8];
    float mx = -3.4e38f;
#pragma unroll
    for (int g = 0; g < 4; ++g) {
        v[2 * g]     = rowp[2 * t + 512 * g];
        v[2 * g + 1] = rowp[2 * t + 512 * g + 1];
    }
#pragma unroll
    for (int i = 0; i < 8; ++i)
        mx = fmaxf(mx, fmaxf(fmaxf(v[i].x, v[i].y), fmaxf(v[i].z, v[i].w)));
    __shared__ float red[8];
#pragma unroll
    for (int off = 32; off >= 1; off >>= 1) mx = fmaxf(mx, __shfl_xor(mx, off));
    if ((t & 63) == 0) red[t >> 6] = mx;
    __syncthreads();
    mx = fmaxf(fmaxf(red[0], red[1]), fmaxf(red[2], red[3]));

    float sum = 0.0f;
#pragma unroll
    for (int i = 0; i < 8; ++i) {
        v[i].x = __expf((v[i].x - mx) * 0.03125f);
        v[i].y = __expf((v[i].y - mx) * 0.03125f);
        v[i].z = __expf((v[i].z - mx) * 0.03125f);
        v[i].w = __expf((v[i].w - mx) * 0.03125f);
        sum += (v[i].x + v[i].y) + (v[i].z + v[i].w);
    }
#pragma unroll
    for (int off = 32; off >= 1; off >>= 1) sum += __shfl_xor(sum, off);
    if ((t & 63) == 0) red[4 + (t >> 6)] = sum;
    __syncthreads();
    float inv = 1.0f / (red[4] + red[5] + red[6] + red[7]);

    f16x8* prow = (f16x8*)(P + (size_t)row * ldp);
#pragma unroll
    for (int g = 0; g < 4; ++g) {
        float4 a = v[2 * g], b = v[2 * g + 1];
        f16x8 o;
        o[0] = (_Float16)(a.x * inv); o[1] = (_Float16)(a.y * inv);
        o[2] = (_Float16)(a.z * inv); o[3] = (_Float16)(a.w * inv);
        o[4] = (_Float16)(b.x * inv); o[5] = (_Float16)(b.y * inv);
        o[6] = (_Float16)(b.z * inv); o[7] = (_Float16)(b.w * inv);
        prow[t + 256 * g] = o;
    }
}

// ---------------------------------------------------------------- launch
extern "C" void kernel_launch(void* const* d_in, const int* in_sizes, int n_in,
                              void* d_out, int out_size, void* d_ws, size_t ws_size,
                              hipStream_t stream) {
    const float* X  = (const float*)d_in[0];  // [8192,1024]
    const float* Wq = (const float*)d_in[1];  // [1024,1024]
    const float* Wk = (const float*)d_in[2];  // [1024,1024]
    float* out = (float*)d_out;               // [8192,1024]

    const long Nt = 8192, D = 1024;
    char* ws = (char*)d_ws;
    const size_t MB = 1024ull * 1024ull;

    // Persistent region (80 MB):
    _Float16* XT  = (_Float16*)(ws + 0);        // 16 MB [1024][8192] = X^T f16
    _Float16* Qhi = (_Float16*)(ws + 16 * MB);  // 16 MB   (dead after S-GEMMs;
    _Float16* Qlo = (_Float16*)(ws + 32 * MB);  //          reused as PK0/PK1)
    _Float16* Khi = (_Float16*)(ws + 48 * MB);
    _Float16* Klo = (_Float16*)(ws + 64 * MB);
    // Transient (dead after projections):
    _Float16* Xhi   = (_Float16*)(ws + 80 * MB);   // 16 MB
    _Float16* Xlo   = (_Float16*)(ws + 96 * MB);   // 16 MB
    _Float16* WqThi = (_Float16*)(ws + 112 * MB);  // 2 MB each, Wq/Wk adjacent
    _Float16* WqTlo = (_Float16*)(ws + 114 * MB);
    _Float16* WkThi = (_Float16*)(ws + 116 * MB);
    _Float16* WkTlo = (_Float16*)(ws + 118 * MB);
    // PV split-K partials (alias dead Qhi..Klo): 2 x 32 MB fp32
    float* PK0 = (float*)(ws + 16 * MB);

    const size_t rowBytes = (size_t)Nt * 4;  // 32 KB per S row
    const bool planA = ws_size >= 208 * MB + 128 * rowBytes;
    _Float16* Pbuf = (_Float16*)(ws + 80 * MB);   // plan A: 128 MB compact P
    float* Sc;
    long chunk;
    if (planA) {
        Sc = (float*)(ws + 208 * MB);
        size_t avail = ws_size - 208 * MB;
        chunk = (long)((avail / rowBytes / 128) * 128);
    } else {
        Sc = (float*)(ws + 80 * MB);
        size_t avail = ws_size > 80 * MB ? ws_size - 80 * MB : 0;
        chunk = (long)((avail / rowBytes / 128) * 128);
        if (chunk < 128) chunk = 128;  // last resort; smaller ws cannot work
    }
    if (chunk > Nt) chunk = Nt;
    // even-size chunks (avoid a tiny low-occupancy tail chunk)
    {
        long nch = (Nt + chunk - 1) / chunk;
        chunk = (((Nt + nch - 1) / nch) + 127) / 128 * 128;
    }

    // 1. prep: one pass over X -> Xhi,Xlo,XT; transpose+split weights
    prep_x<<<dim3(32, 256), dim3(32, 8), 0, stream>>>(X, Xhi, Xlo, XT,
                                                      (int)Nt, (int)D);
    transpose_split<<<dim3(32, 32), dim3(32, 8), 0, stream>>>(Wq, WqThi, WqTlo,
                                                              (int)D, (int)D);
    transpose_split<<<dim3(32, 32), dim3(32, 8), 0, stream>>>(Wk, WkThi, WkTlo,
                                                              (int)D, (int)D);

    // 2. fused Q+K projections (3-term split), z=0 -> Q, z=1 -> K.
    //    zB = WkThi-WqThi = 4 MB = 2M halves; zC = Khi-Qhi = 16M halves.
    //    1024 blocks at 4/CU -> fully resident, no tail wave.
    gemm_bt<3, 1, 1, 32><<<dim3(Nt / TM, D / TN, 2), 256, 0, stream>>>(
        Xhi, Xlo, WqThi, WqTlo, nullptr, Qhi, Qlo, D, D, D, (int)D,
        0, (long)(4 * MB / 2), (long)(32 * MB / 2));

    // 3. chunks: S = Q@K^T (3-term, fp32), softmax -> P f16.
    //    SWAP=0: grid.x = 64 col-blocks (B = K-splits, 32 MB, co-located).
    long done = 0;
    while (done < Nt) {
        long cur = Nt - done < chunk ? Nt - done : chunk;
        gemm_bt<3, 0, 0, 32><<<dim3(Nt / TN, cur / TM, 1), 256, 0, stream>>>(
            Qhi + done * D, Qlo + done * D, Khi, Klo, Sc, nullptr, nullptr,
            D, D, Nt, (int)D, 0, 0, 0);
        if (planA) {
            softmax_rows<<<(int)cur, 256, 0, stream>>>(Sc, Pbuf + done * Nt,
                                                       Nt, (int)Nt);
        } else {
            softmax_rows<<<(int)cur, 256, 0, stream>>>(Sc, (_Float16*)Sc,
                                                       2 * Nt, (int)Nt);
            gemm_bt<1, 0, 1, 64><<<dim3(cur / TM, D / TN, 1), 256, 0, stream>>>(
                (const _Float16*)Sc, nullptr, XT, nullptr,
                out + done * D, nullptr, nullptr, 2 * Nt, Nt, D, (int)Nt,
                0, 0, 0);
        }
        done += cur;
    }

    // 4. plan A: PV split-K=2, BK=64, SWAP=1 (R6's measured best: grid
    //    (64,8,2) -> id%8 = row-block%8, P row-tile co-located per XCD;
    //    0 LDS conflicts with the 16x16 read pattern). Partials in the
    //    dead Q/K region, then reduce.
    if (planA) {
        gemm_bt<1, 0, 1, 64><<<dim3(Nt / TM, D / TN, 2), 256, 0, stream>>>(
            Pbuf, nullptr, XT, nullptr, PK0, nullptr, nullptr,
            Nt, Nt, D, (int)(Nt / 2),
            Nt / 2, Nt / 2, Nt * D);
        add_rows<<<1024, 256, 0, stream>>>(PK0, PK0 + Nt * D, out, Nt * D / 4);
    }
}